// Round 1
// baseline (809.975 us; speedup 1.0000x reference)
//
#include <hip/hip_runtime.h>
#include <hip/hip_bf16.h>

#define NE   4096      // hyperedges
#define D1   512       // H1
#define D2   128       // H2
#define NNZV 131072    // nnz per incidence
#define MTOT 13312     // NA+NK+NV

typedef __attribute__((ext_vector_type(8))) short bf16x8;
typedef __attribute__((ext_vector_type(4))) float f32x4;

struct Params {
  const int*   rows[3]; const int* cols[3]; const float* vals[3];
  const float* Wn[3];  const float* bn[3];
  const float* Wzm[3]; const float* bzm[3];
  const float* Wzs[3]; const float* bzs[3];
  const float* We[3];  const float* be[3];
  const float* eps[3];
  const float* Watt; const float* batt; const float* uatt;
  const float* Wem;  const float* bem;  const float* Wes; const float* bes;
  const float* eps_e;
  int* cnt[6]; int* ptr[6]; int* cur[6]; int2* spair[6];
  float* h[3]; float* e[3];
  float* scores;
  __hip_bfloat16* Zbf; __hip_bfloat16* Zmbf; __hip_bfloat16* zebf; __hip_bfloat16* zembf;
  float* out;
  int rowbase[3];
};

// sub = type*2 + dir;  dir0: segment by rows, gather Wn[cols];  dir1: segment by cols, gather We[rows]
__device__ __forceinline__ int nseg_of(int sub) {
  if (sub & 1) return NE;
  int t = sub >> 1;
  return t == 0 ? 8192 : (t == 1 ? 4096 : 1024);
}

__global__ void hist_kernel(Params p) {
  int i = blockIdx.x * blockDim.x + threadIdx.x;
  if (i >= 6 * NNZV) return;
  int sub = i >> 17, idx = i & (NNZV - 1);
  int type = sub >> 1, dir = sub & 1;
  int seg = dir ? p.cols[type][idx] : p.rows[type][idx];
  atomicAdd(&p.cnt[sub][seg], 1);
}

__global__ __launch_bounds__(1024) void scan_kernel(Params p) {
  int sub = blockIdx.x;
  int n = nseg_of(sub);
  const int* cnt = p.cnt[sub];
  int* ptr = p.ptr[sub];
  int* cur = p.cur[sub];
  __shared__ int lds[1024];
  int tid = threadIdx.x;
  int per = (n + 1023) >> 10;
  int base = tid * per;
  int s = 0;
  for (int q = 0; q < per; ++q) { int ix = base + q; if (ix < n) s += cnt[ix]; }
  lds[tid] = s;
  __syncthreads();
  for (int off = 1; off < 1024; off <<= 1) {
    int v = (tid >= off) ? lds[tid - off] : 0;
    __syncthreads();
    lds[tid] += v;
    __syncthreads();
  }
  int prefix = (tid == 0) ? 0 : lds[tid - 1];
  for (int q = 0; q < per; ++q) {
    int ix = base + q;
    if (ix < n) { int c = cnt[ix]; ptr[ix] = prefix; cur[ix] = prefix; prefix += c; }
  }
  if (tid == 1023) ptr[n] = lds[1023];
}

__global__ void scatter_kernel(Params p) {
  int i = blockIdx.x * blockDim.x + threadIdx.x;
  if (i >= 6 * NNZV) return;
  int sub = i >> 17, idx = i & (NNZV - 1);
  int type = sub >> 1, dir = sub & 1;
  int seg = dir ? p.cols[type][idx] : p.rows[type][idx];
  int oth = dir ? p.rows[type][idx] : p.cols[type][idx];
  int pos = atomicAdd(&p.cur[sub][seg], 1);
  p.spair[sub][pos] = make_int2(oth, __float_as_int(p.vals[type][idx]));
}

// one block (128 thr) per output row: out[seg][0..511] = tanh(sum val*W[idx] + bias)
__global__ __launch_bounds__(128) void spmm_kernel(Params p) {
  int b = blockIdx.x;
  int sub, seg;
  if      (b <  8192) { sub = 0; seg = b;         }
  else if (b < 12288) { sub = 1; seg = b - 8192;  }
  else if (b < 16384) { sub = 2; seg = b - 12288; }
  else if (b < 20480) { sub = 3; seg = b - 16384; }
  else if (b < 21504) { sub = 4; seg = b - 20480; }
  else                { sub = 5; seg = b - 21504; }
  int type = sub >> 1, dir = sub & 1;
  const float* W    = dir ? p.We[type] : p.Wn[type];
  const float* bias = dir ? p.be[type] : p.bn[type];
  float* outp       = dir ? p.e[type]  : p.h[type];
  const int*  ptr  = p.ptr[sub];
  const int2* pair = p.spair[sub];
  int j4 = threadIdx.x * 4;
  float4 acc = {0.f, 0.f, 0.f, 0.f};
  int q0 = ptr[seg], q1 = ptr[seg + 1];
  for (int q = q0; q < q1; ++q) {
    int2 pr = pair[q];
    float v = __int_as_float(pr.y);
    const float4 wv = *(const float4*)&W[(size_t)pr.x * D1 + j4];
    acc.x += v * wv.x; acc.y += v * wv.y; acc.z += v * wv.z; acc.w += v * wv.w;
  }
  const float4 bv = *(const float4*)&bias[j4];
  float4 o;
  o.x = tanhf(acc.x + bv.x); o.y = tanhf(acc.y + bv.y);
  o.z = tanhf(acc.z + bv.z); o.w = tanhf(acc.w + bv.w);
  *(float4*)&outp[(size_t)seg * D1 + j4] = o;
}

// 32 rows/block; thread: 2 cols x 2 mats x 8 rows.  zm/zs/z + bf16 stacked outputs.
__global__ __launch_bounds__(256) void zmzs_kernel(Params p) {
  __shared__ __align__(16) float hs[32 * D1];   // 64 KB
  int b = blockIdx.x;
  int type, blk;
  if      (b < 256) { type = 0; blk = b;       }
  else if (b < 384) { type = 1; blk = b - 256; }
  else              { type = 2; blk = b - 384; }
  int row0 = blk * 32;
  const float* hsrc = p.h[type] + (size_t)row0 * D1;
  for (int i4 = threadIdx.x; i4 < 32 * (D1 / 4); i4 += 256)
    ((float4*)hs)[i4] = ((const float4*)hsrc)[i4];
  __syncthreads();
  int jp = threadIdx.x & 63, rg = threadIdx.x >> 6;
  int j = jp * 2;
  const float* Wm = p.Wzm[type];
  const float* Ws = p.Wzs[type];
  float am[8][2], as[8][2];
#pragma unroll
  for (int r = 0; r < 8; ++r) { am[r][0]=am[r][1]=as[r][0]=as[r][1]=0.f; }
  for (int hh = 0; hh < D1; hh += 4) {
    float2 wm[4], ws[4];
#pragma unroll
    for (int q = 0; q < 4; ++q) {
      wm[q] = *(const float2*)&Wm[(size_t)(hh + q) * D2 + j];
      ws[q] = *(const float2*)&Ws[(size_t)(hh + q) * D2 + j];
    }
#pragma unroll
    for (int r = 0; r < 8; ++r) {
      const float4 ev = *(const float4*)&hs[(rg * 8 + r) * D1 + hh];
      am[r][0] += ev.x*wm[0].x + ev.y*wm[1].x + ev.z*wm[2].x + ev.w*wm[3].x;
      am[r][1] += ev.x*wm[0].y + ev.y*wm[1].y + ev.z*wm[2].y + ev.w*wm[3].y;
      as[r][0] += ev.x*ws[0].x + ev.y*ws[1].x + ev.z*ws[2].x + ev.w*ws[3].x;
      as[r][1] += ev.x*ws[0].y + ev.y*ws[1].y + ev.z*ws[2].y + ev.w*ws[3].y;
    }
  }
  int base = p.rowbase[type];
  const float* eps = p.eps[type];
  float bm0 = p.bzm[type][j], bm1 = p.bzm[type][j+1];
  float bs0 = p.bzs[type][j], bs1 = p.bzs[type][j+1];
#pragma unroll
  for (int r = 0; r < 8; ++r) {
    int row = row0 + rg * 8 + r;
    float zm0 = am[r][0] + bm0, zm1 = am[r][1] + bm1;
    float zs0 = as[r][0] + bs0, zs1 = as[r][1] + bs1;
    float e0v = eps[(size_t)row * D2 + j], e1v = eps[(size_t)row * D2 + j + 1];
    float z0 = zm0 + e0v * expf(zs0), z1 = zm1 + e1v * expf(zs1);
    size_t oi = (size_t)(base + row) * D2 + j;
    p.Zmbf[oi]   = __float2bfloat16(zm0); p.Zmbf[oi+1] = __float2bfloat16(zm1);
    p.Zbf[oi]    = __float2bfloat16(z0);  p.Zbf[oi+1]  = __float2bfloat16(z1);
  }
}

// 8 edges/block (24 rows); wave w owns rows w*6..w*6+5, lane owns 4 d-cols; wave shuffle-reduce over d.
__global__ __launch_bounds__(256) void scores_kernel(Params p) {
  __shared__ __align__(16) float em[24 * D1];   // 48 KB
  int e0 = blockIdx.x * 8;
  for (int i4 = threadIdx.x; i4 < 24 * (D1 / 4); i4 += 256) {
    int r = i4 >> 7, h4 = i4 & 127;
    int el = r / 3, t = r - el * 3;
    ((float4*)em)[i4] = ((const float4*)(p.e[t] + (size_t)(e0 + el) * D1))[h4];
  }
  __syncthreads();
  int lane = threadIdx.x & 63, w = threadIdx.x >> 6;
  int d0 = lane * 4;
  float acc[6][4];
#pragma unroll
  for (int r = 0; r < 6; ++r) { acc[r][0]=acc[r][1]=acc[r][2]=acc[r][3]=0.f; }
  for (int hh = 0; hh < D1; hh += 4) {
    float4 w0 = *(const float4*)&p.Watt[(size_t)(hh+0) * 256 + d0];
    float4 w1 = *(const float4*)&p.Watt[(size_t)(hh+1) * 256 + d0];
    float4 w2 = *(const float4*)&p.Watt[(size_t)(hh+2) * 256 + d0];
    float4 w3 = *(const float4*)&p.Watt[(size_t)(hh+3) * 256 + d0];
#pragma unroll
    for (int r = 0; r < 6; ++r) {
      const float4 ev = *(const float4*)&em[(w * 6 + r) * D1 + hh];
      acc[r][0] += ev.x*w0.x + ev.y*w1.x + ev.z*w2.x + ev.w*w3.x;
      acc[r][1] += ev.x*w0.y + ev.y*w1.y + ev.z*w2.y + ev.w*w3.y;
      acc[r][2] += ev.x*w0.z + ev.y*w1.z + ev.z*w2.z + ev.w*w3.z;
      acc[r][3] += ev.x*w0.w + ev.y*w1.w + ev.z*w2.w + ev.w*w3.w;
    }
  }
  const float4 u4 = *(const float4*)&p.uatt[d0];
  const float4 b4 = *(const float4*)&p.batt[d0];
#pragma unroll
  for (int r = 0; r < 6; ++r) {
    float s = u4.x * tanhf(acc[r][0] + b4.x) + u4.y * tanhf(acc[r][1] + b4.y)
            + u4.z * tanhf(acc[r][2] + b4.z) + u4.w * tanhf(acc[r][3] + b4.w);
#pragma unroll
    for (int off = 32; off > 0; off >>= 1) s += __shfl_down(s, off, 64);
    if (lane == 0) p.scores[e0 * 3 + w * 6 + r] = s;
  }
}

// 16 edges/block: softmax over 3 types, weighted edge embed, zem/zes/ze (bf16 out)
__global__ __launch_bounds__(256) void combine_kernel(Params p) {
  __shared__ __align__(16) float ee[16 * D1];   // 32 KB
  __shared__ float alpha[16][3];
  int e0 = blockIdx.x * 16;
  int tid = threadIdx.x;
  if (tid < 16) {
    float s0 = p.scores[(e0 + tid) * 3 + 0];
    float s1 = p.scores[(e0 + tid) * 3 + 1];
    float s2 = p.scores[(e0 + tid) * 3 + 2];
    float m = fmaxf(s0, fmaxf(s1, s2));
    float a0 = expf(s0 - m), a1 = expf(s1 - m), a2 = expf(s2 - m);
    float inv = 1.f / (a0 + a1 + a2);
    alpha[tid][0] = a0 * inv; alpha[tid][1] = a1 * inv; alpha[tid][2] = a2 * inv;
  }
  __syncthreads();
  for (int i4 = tid; i4 < 16 * (D1 / 4); i4 += 256) {
    int el = i4 >> 7, h4 = i4 & 127;
    size_t b4i = (size_t)(e0 + el) * (D1 / 4) + h4;
    float4 va = ((const float4*)p.e[0])[b4i];
    float4 vk = ((const float4*)p.e[1])[b4i];
    float4 vv = ((const float4*)p.e[2])[b4i];
    float a0 = alpha[el][0], a1 = alpha[el][1], a2 = alpha[el][2];
    float4 o;
    o.x = a0*va.x + a1*vk.x + a2*vv.x;
    o.y = a0*va.y + a1*vk.y + a2*vv.y;
    o.z = a0*va.z + a1*vk.z + a2*vv.z;
    o.w = a0*va.w + a1*vk.w + a2*vv.w;
    ((float4*)ee)[i4] = o;
  }
  __syncthreads();
  int jp = tid & 63, eg = tid >> 6;
  int j = jp * 2;
  float am[4][2], as[4][2];
#pragma unroll
  for (int r = 0; r < 4; ++r) { am[r][0]=am[r][1]=as[r][0]=as[r][1]=0.f; }
  for (int hh = 0; hh < D1; hh += 4) {
    float2 wm[4], ws[4];
#pragma unroll
    for (int q = 0; q < 4; ++q) {
      wm[q] = *(const float2*)&p.Wem[(size_t)(hh + q) * D2 + j];
      ws[q] = *(const float2*)&p.Wes[(size_t)(hh + q) * D2 + j];
    }
#pragma unroll
    for (int r = 0; r < 4; ++r) {
      const float4 ev = *(const float4*)&ee[(eg * 4 + r) * D1 + hh];
      am[r][0] += ev.x*wm[0].x + ev.y*wm[1].x + ev.z*wm[2].x + ev.w*wm[3].x;
      am[r][1] += ev.x*wm[0].y + ev.y*wm[1].y + ev.z*wm[2].y + ev.w*wm[3].y;
      as[r][0] += ev.x*ws[0].x + ev.y*ws[1].x + ev.z*ws[2].x + ev.w*ws[3].x;
      as[r][1] += ev.x*ws[0].y + ev.y*ws[1].y + ev.z*ws[2].y + ev.w*ws[3].y;
    }
  }
  float bm0 = p.bem[j], bm1 = p.bem[j+1], bs0 = p.bes[j], bs1 = p.bes[j+1];
#pragma unroll
  for (int r = 0; r < 4; ++r) {
    int e = e0 + eg * 4 + r;
    float zm0 = am[r][0] + bm0, zm1 = am[r][1] + bm1;
    float zs0 = as[r][0] + bs0, zs1 = as[r][1] + bs1;
    float e0v = p.eps_e[(size_t)e * D2 + j], e1v = p.eps_e[(size_t)e * D2 + j + 1];
    float z0 = zm0 + e0v * expf(zs0), z1 = zm1 + e1v * expf(zs1);
    size_t oi = (size_t)e * D2 + j;
    p.zembf[oi]   = __float2bfloat16(zm0); p.zembf[oi+1] = __float2bfloat16(zm1);
    p.zebf[oi]    = __float2bfloat16(z0);  p.zebf[oi+1]  = __float2bfloat16(z1);
  }
}

// out[M,4096] = A[M,128] @ B[4096,128]^T, bf16 MFMA 16x16x32.  Block: 64x64 tile, 4 waves x (16x64).
__global__ __launch_bounds__(256) void decode_kernel(Params p) {
  int which = blockIdx.z;
  const __hip_bfloat16* A = which ? p.Zmbf  : p.Zbf;
  const __hip_bfloat16* B = which ? p.zembf : p.zebf;
  float* C = p.out + (size_t)which * MTOT * NE;
  int n0 = blockIdx.x * 64;
  int m0 = blockIdx.y * 64;
  int wid  = threadIdx.x >> 6;
  int lane = threadIdx.x & 63;
  int rloc = lane & 15;
  int kg   = lane >> 4;
  int mrow = m0 + wid * 16 + rloc;
  bf16x8 a[4];
#pragma unroll
  for (int kk = 0; kk < 4; ++kk)
    a[kk] = *(const bf16x8*)(A + (size_t)mrow * D2 + kk * 32 + kg * 8);
  f32x4 acc[4];
  f32x4 zero = {0.f, 0.f, 0.f, 0.f};
#pragma unroll
  for (int nf = 0; nf < 4; ++nf) acc[nf] = zero;
#pragma unroll
  for (int nf = 0; nf < 4; ++nf) {
    int ncol = n0 + nf * 16 + rloc;
#pragma unroll
    for (int kk = 0; kk < 4; ++kk) {
      bf16x8 bv = *(const bf16x8*)(B + (size_t)ncol * D2 + kk * 32 + kg * 8);
      acc[nf] = __builtin_amdgcn_mfma_f32_16x16x32_bf16(a[kk], bv, acc[nf], 0, 0, 0);
    }
  }
  int r0 = m0 + wid * 16 + (lane >> 4) * 4;
#pragma unroll
  for (int nf = 0; nf < 4; ++nf) {
    int cc = n0 + nf * 16 + rloc;
#pragma unroll
    for (int jj = 0; jj < 4; ++jj)
      C[(size_t)(r0 + jj) * NE + cc] = acc[nf][jj];
  }
}

extern "C" void kernel_launch(void* const* d_in, const int* in_sizes, int n_in,
                              void* d_out, int out_size, void* d_ws, size_t ws_size,
                              hipStream_t stream) {
  (void)in_sizes; (void)n_in; (void)out_size; (void)ws_size;
  static const int Ns[3] = {8192, 4096, 1024};
  static const int NsegH[6] = {8192, 4096, 4096, 4096, 1024, 4096};

  Params p;
  for (int t = 0; t < 3; ++t) {
    const int o = t * 12;
    p.rows[t] = (const int*)d_in[o + 0];
    p.cols[t] = (const int*)d_in[o + 1];
    p.vals[t] = (const float*)d_in[o + 2];
    p.Wn[t]   = (const float*)d_in[o + 3];
    p.bn[t]   = (const float*)d_in[o + 4];
    p.Wzm[t]  = (const float*)d_in[o + 5];
    p.bzm[t]  = (const float*)d_in[o + 6];
    p.Wzs[t]  = (const float*)d_in[o + 7];
    p.bzs[t]  = (const float*)d_in[o + 8];
    p.We[t]   = (const float*)d_in[o + 9];
    p.be[t]   = (const float*)d_in[o + 10];
    p.eps[t]  = (const float*)d_in[o + 11];
  }
  p.Watt  = (const float*)d_in[36];
  p.batt  = (const float*)d_in[37];
  p.uatt  = (const float*)d_in[38];
  p.Wem   = (const float*)d_in[39];
  p.bem   = (const float*)d_in[40];
  p.Wes   = (const float*)d_in[41];
  p.bes   = (const float*)d_in[42];
  p.eps_e = (const float*)d_in[43];
  p.out = (float*)d_out;
  p.rowbase[0] = 0; p.rowbase[1] = 8192; p.rowbase[2] = 12288;

  char* ws = (char*)d_ws;
  size_t off = 0;
  auto alloc = [&](size_t bytes) -> char* {
    char* r = ws + off;
    off += (bytes + 255) & ~(size_t)255;
    return r;
  };
  // counter arrays first: one contiguous region, zeroed each call
  for (int s = 0; s < 6; ++s) p.cnt[s] = (int*)alloc((size_t)(NsegH[s] + 1) * 4);
  size_t cnt_bytes = off;
  for (int s = 0; s < 6; ++s) {
    p.ptr[s]   = (int*)alloc((size_t)(NsegH[s] + 1) * 4);
    p.cur[s]   = (int*)alloc((size_t)(NsegH[s] + 1) * 4);
    p.spair[s] = (int2*)alloc((size_t)NNZV * 8);
  }
  for (int t = 0; t < 3; ++t) p.h[t] = (float*)alloc((size_t)Ns[t] * D1 * 4);
  for (int t = 0; t < 3; ++t) p.e[t] = (float*)alloc((size_t)NE * D1 * 4);
  p.scores = (float*)alloc((size_t)NE * 3 * 4);
  p.Zbf    = (__hip_bfloat16*)alloc((size_t)MTOT * D2 * 2);
  p.Zmbf   = (__hip_bfloat16*)alloc((size_t)MTOT * D2 * 2);
  p.zebf   = (__hip_bfloat16*)alloc((size_t)NE * D2 * 2);
  p.zembf  = (__hip_bfloat16*)alloc((size_t)NE * D2 * 2);

  hipMemsetAsync(d_ws, 0, cnt_bytes, stream);
  hist_kernel   <<<(6 * NNZV + 255) / 256, 256, 0, stream>>>(p);
  scan_kernel   <<<6, 1024, 0, stream>>>(p);
  scatter_kernel<<<(6 * NNZV + 255) / 256, 256, 0, stream>>>(p);
  spmm_kernel   <<<25600, 128, 0, stream>>>(p);
  zmzs_kernel   <<<416, 256, 0, stream>>>(p);
  scores_kernel <<<512, 256, 0, stream>>>(p);
  combine_kernel<<<256, 256, 0, stream>>>(p);
  decode_kernel <<<dim3(64, 208, 2), 256, 0, stream>>>(p);
}

// Round 3
// 695.052 us; speedup vs baseline: 1.1653x; 1.1653x over previous
//
#include <hip/hip_runtime.h>
#include <hip/hip_bf16.h>

#define NE   4096      // hyperedges
#define D1   512       // H1
#define D2   128       // H2
#define NNZV 131072    // nnz per incidence
#define MTOT 13312     // NA+NK+NV

typedef __attribute__((ext_vector_type(8))) short bf16x8;
typedef __attribute__((ext_vector_type(4))) float f32x4;

struct Params {
  const int*   rows[3]; const int* cols[3]; const float* vals[3];
  const float* Wn[3];  const float* bn[3];
  const float* Wzm[3]; const float* bzm[3];
  const float* Wzs[3]; const float* bzs[3];
  const float* We[3];  const float* be[3];
  const float* eps[3];
  const float* Watt; const float* batt; const float* uatt;
  const float* Wem;  const float* bem;  const float* Wes; const float* bes;
  const float* eps_e;
  int* cnt[6]; int* ptr[6]; int* cur[6]; int2* spair[6];
  float* h[3]; float* e[3];
  float* scores;
  __hip_bfloat16* Zbf; __hip_bfloat16* Zmbf; __hip_bfloat16* zebf; __hip_bfloat16* zembf;
  float* out;
  int rowbase[3];
};

// sub = type*2 + dir;  dir0: segment by rows, gather Wn[cols];  dir1: segment by cols, gather We[rows]
__device__ __forceinline__ int nseg_of(int sub) {
  if (sub & 1) return NE;
  int t = sub >> 1;
  return t == 0 ? 8192 : (t == 1 ? 4096 : 1024);
}

__global__ void hist_kernel(Params p) {
  int i = blockIdx.x * blockDim.x + threadIdx.x;
  if (i >= 6 * NNZV) return;
  int sub = i >> 17, idx = i & (NNZV - 1);
  int type = sub >> 1, dir = sub & 1;
  int seg = dir ? p.cols[type][idx] : p.rows[type][idx];
  atomicAdd(&p.cnt[sub][seg], 1);
}

__global__ __launch_bounds__(1024) void scan_kernel(Params p) {
  int sub = blockIdx.x;
  int n = nseg_of(sub);
  const int* cnt = p.cnt[sub];
  int* ptr = p.ptr[sub];
  int* cur = p.cur[sub];
  __shared__ int lds[1024];
  int tid = threadIdx.x;
  int per = (n + 1023) >> 10;
  int base = tid * per;
  int s = 0;
  for (int q = 0; q < per; ++q) { int ix = base + q; if (ix < n) s += cnt[ix]; }
  lds[tid] = s;
  __syncthreads();
  for (int off = 1; off < 1024; off <<= 1) {
    int v = (tid >= off) ? lds[tid - off] : 0;
    __syncthreads();
    lds[tid] += v;
    __syncthreads();
  }
  int prefix = (tid == 0) ? 0 : lds[tid - 1];
  for (int q = 0; q < per; ++q) {
    int ix = base + q;
    if (ix < n) { int c = cnt[ix]; ptr[ix] = prefix; cur[ix] = prefix; prefix += c; }
  }
  if (tid == 1023) ptr[n] = lds[1023];
}

__global__ void scatter_kernel(Params p) {
  int i = blockIdx.x * blockDim.x + threadIdx.x;
  if (i >= 6 * NNZV) return;
  int sub = i >> 17, idx = i & (NNZV - 1);
  int type = sub >> 1, dir = sub & 1;
  int seg = dir ? p.cols[type][idx] : p.rows[type][idx];
  int oth = dir ? p.rows[type][idx] : p.cols[type][idx];
  int pos = atomicAdd(&p.cur[sub][seg], 1);
  p.spair[sub][pos] = make_int2(oth, __float_as_int(p.vals[type][idx]));
}

// one block (128 thr) per output row: out[seg][0..511] = tanh(sum val*W[idx] + bias)
// unroll-4 gather pipeline: 4 independent W-row loads in flight per iteration
__global__ __launch_bounds__(128) void spmm_kernel(Params p) {
  int b = blockIdx.x;
  int sub, seg;
  if      (b <  8192) { sub = 0; seg = b;         }
  else if (b < 12288) { sub = 1; seg = b - 8192;  }
  else if (b < 16384) { sub = 2; seg = b - 12288; }
  else if (b < 20480) { sub = 3; seg = b - 16384; }
  else if (b < 21504) { sub = 4; seg = b - 20480; }
  else                { sub = 5; seg = b - 21504; }
  int type = sub >> 1, dir = sub & 1;
  const float* W    = dir ? p.We[type] : p.Wn[type];
  const float* bias = dir ? p.be[type] : p.bn[type];
  float* outp       = dir ? p.e[type]  : p.h[type];
  const int*  ptr  = p.ptr[sub];
  const int2* pair = p.spair[sub];
  int j4 = threadIdx.x * 4;
  float4 acc = {0.f, 0.f, 0.f, 0.f};
  int q0 = ptr[seg], q1 = ptr[seg + 1];
  int q = q0;
  for (; q + 4 <= q1; q += 4) {
    int2 pr0 = pair[q], pr1 = pair[q + 1], pr2 = pair[q + 2], pr3 = pair[q + 3];
    float v0 = __int_as_float(pr0.y), v1 = __int_as_float(pr1.y);
    float v2 = __int_as_float(pr2.y), v3 = __int_as_float(pr3.y);
    const float4 w0 = *(const float4*)&W[(size_t)pr0.x * D1 + j4];
    const float4 w1 = *(const float4*)&W[(size_t)pr1.x * D1 + j4];
    const float4 w2 = *(const float4*)&W[(size_t)pr2.x * D1 + j4];
    const float4 w3 = *(const float4*)&W[(size_t)pr3.x * D1 + j4];
    acc.x += v0 * w0.x + v1 * w1.x + v2 * w2.x + v3 * w3.x;
    acc.y += v0 * w0.y + v1 * w1.y + v2 * w2.y + v3 * w3.y;
    acc.z += v0 * w0.z + v1 * w1.z + v2 * w2.z + v3 * w3.z;
    acc.w += v0 * w0.w + v1 * w1.w + v2 * w2.w + v3 * w3.w;
  }
  for (; q < q1; ++q) {
    int2 pr = pair[q];
    float v = __int_as_float(pr.y);
    const float4 wv = *(const float4*)&W[(size_t)pr.x * D1 + j4];
    acc.x += v * wv.x; acc.y += v * wv.y; acc.z += v * wv.z; acc.w += v * wv.w;
  }
  const float4 bv = *(const float4*)&bias[j4];
  float4 o;
  o.x = tanhf(acc.x + bv.x); o.y = tanhf(acc.y + bv.y);
  o.z = tanhf(acc.z + bv.z); o.w = tanhf(acc.w + bv.w);
  *(float4*)&outp[(size_t)seg * D1 + j4] = o;
}

// 32 rows/block; thread: 2 cols x 2 mats x 8 rows.  zm/zs/z + bf16 stacked outputs.
__global__ __launch_bounds__(256) void zmzs_kernel(Params p) {
  __shared__ __align__(16) float hs[32 * D1];   // 64 KB
  int b = blockIdx.x;
  int type, blk;
  if      (b < 256) { type = 0; blk = b;       }
  else if (b < 384) { type = 1; blk = b - 256; }
  else              { type = 2; blk = b - 384; }
  int row0 = blk * 32;
  const float* hsrc = p.h[type] + (size_t)row0 * D1;
  for (int i4 = threadIdx.x; i4 < 32 * (D1 / 4); i4 += 256)
    ((float4*)hs)[i4] = ((const float4*)hsrc)[i4];
  __syncthreads();
  int jp = threadIdx.x & 63, rg = threadIdx.x >> 6;
  int j = jp * 2;
  const float* Wm = p.Wzm[type];
  const float* Ws = p.Wzs[type];
  float am[8][2], as[8][2];
#pragma unroll
  for (int r = 0; r < 8; ++r) { am[r][0]=am[r][1]=as[r][0]=as[r][1]=0.f; }
  for (int hh = 0; hh < D1; hh += 4) {
    float2 wm[4], ws[4];
#pragma unroll
    for (int q = 0; q < 4; ++q) {
      wm[q] = *(const float2*)&Wm[(size_t)(hh + q) * D2 + j];
      ws[q] = *(const float2*)&Ws[(size_t)(hh + q) * D2 + j];
    }
#pragma unroll
    for (int r = 0; r < 8; ++r) {
      const float4 ev = *(const float4*)&hs[(rg * 8 + r) * D1 + hh];
      am[r][0] += ev.x*wm[0].x + ev.y*wm[1].x + ev.z*wm[2].x + ev.w*wm[3].x;
      am[r][1] += ev.x*wm[0].y + ev.y*wm[1].y + ev.z*wm[2].y + ev.w*wm[3].y;
      as[r][0] += ev.x*ws[0].x + ev.y*ws[1].x + ev.z*ws[2].x + ev.w*ws[3].x;
      as[r][1] += ev.x*ws[0].y + ev.y*ws[1].y + ev.z*ws[2].y + ev.w*ws[3].y;
    }
  }
  int base = p.rowbase[type];
  const float* eps = p.eps[type];
  float bm0 = p.bzm[type][j], bm1 = p.bzm[type][j+1];
  float bs0 = p.bzs[type][j], bs1 = p.bzs[type][j+1];
#pragma unroll
  for (int r = 0; r < 8; ++r) {
    int row = row0 + rg * 8 + r;
    float zm0 = am[r][0] + bm0, zm1 = am[r][1] + bm1;
    float zs0 = as[r][0] + bs0, zs1 = as[r][1] + bs1;
    float e0v = eps[(size_t)row * D2 + j], e1v = eps[(size_t)row * D2 + j + 1];
    float z0 = zm0 + e0v * expf(zs0), z1 = zm1 + e1v * expf(zs1);
    size_t oi = (size_t)(base + row) * D2 + j;
    p.Zmbf[oi]   = __float2bfloat16(zm0); p.Zmbf[oi+1] = __float2bfloat16(zm1);
    p.Zbf[oi]    = __float2bfloat16(z0);  p.Zbf[oi+1]  = __float2bfloat16(z1);
  }
}

// 8 edges/block (24 rows); wave w owns rows w*6..w*6+5, lane owns 4 d-cols; wave shuffle-reduce over d.
__global__ __launch_bounds__(256) void scores_kernel(Params p) {
  __shared__ __align__(16) float em[24 * D1];   // 48 KB
  int e0 = blockIdx.x * 8;
  for (int i4 = threadIdx.x; i4 < 24 * (D1 / 4); i4 += 256) {
    int r = i4 >> 7, h4 = i4 & 127;
    int el = r / 3, t = r - el * 3;
    ((float4*)em)[i4] = ((const float4*)(p.e[t] + (size_t)(e0 + el) * D1))[h4];
  }
  __syncthreads();
  int lane = threadIdx.x & 63, w = threadIdx.x >> 6;
  int d0 = lane * 4;
  float acc[6][4];
#pragma unroll
  for (int r = 0; r < 6; ++r) { acc[r][0]=acc[r][1]=acc[r][2]=acc[r][3]=0.f; }
  for (int hh = 0; hh < D1; hh += 4) {
    float4 w0 = *(const float4*)&p.Watt[(size_t)(hh+0) * 256 + d0];
    float4 w1 = *(const float4*)&p.Watt[(size_t)(hh+1) * 256 + d0];
    float4 w2 = *(const float4*)&p.Watt[(size_t)(hh+2) * 256 + d0];
    float4 w3 = *(const float4*)&p.Watt[(size_t)(hh+3) * 256 + d0];
#pragma unroll
    for (int r = 0; r < 6; ++r) {
      const float4 ev = *(const float4*)&em[(w * 6 + r) * D1 + hh];
      acc[r][0] += ev.x*w0.x + ev.y*w1.x + ev.z*w2.x + ev.w*w3.x;
      acc[r][1] += ev.x*w0.y + ev.y*w1.y + ev.z*w2.y + ev.w*w3.y;
      acc[r][2] += ev.x*w0.z + ev.y*w1.z + ev.z*w2.z + ev.w*w3.z;
      acc[r][3] += ev.x*w0.w + ev.y*w1.w + ev.z*w2.w + ev.w*w3.w;
    }
  }
  const float4 u4 = *(const float4*)&p.uatt[d0];
  const float4 b4 = *(const float4*)&p.batt[d0];
#pragma unroll
  for (int r = 0; r < 6; ++r) {
    float s = u4.x * tanhf(acc[r][0] + b4.x) + u4.y * tanhf(acc[r][1] + b4.y)
            + u4.z * tanhf(acc[r][2] + b4.z) + u4.w * tanhf(acc[r][3] + b4.w);
#pragma unroll
    for (int off = 32; off > 0; off >>= 1) s += __shfl_down(s, off, 64);
    if (lane == 0) p.scores[e0 * 3 + w * 6 + r] = s;
  }
}

// 16 edges/block: softmax over 3 types, weighted edge embed, zem/zes/ze (bf16 out)
__global__ __launch_bounds__(256) void combine_kernel(Params p) {
  __shared__ __align__(16) float ee[16 * D1];   // 32 KB
  __shared__ float alpha[16][3];
  int e0 = blockIdx.x * 16;
  int tid = threadIdx.x;
  if (tid < 16) {
    float s0 = p.scores[(e0 + tid) * 3 + 0];
    float s1 = p.scores[(e0 + tid) * 3 + 1];
    float s2 = p.scores[(e0 + tid) * 3 + 2];
    float m = fmaxf(s0, fmaxf(s1, s2));
    float a0 = expf(s0 - m), a1 = expf(s1 - m), a2 = expf(s2 - m);
    float inv = 1.f / (a0 + a1 + a2);
    alpha[tid][0] = a0 * inv; alpha[tid][1] = a1 * inv; alpha[tid][2] = a2 * inv;
  }
  __syncthreads();
  for (int i4 = tid; i4 < 16 * (D1 / 4); i4 += 256) {
    int el = i4 >> 7, h4 = i4 & 127;
    size_t b4i = (size_t)(e0 + el) * (D1 / 4) + h4;
    float4 va = ((const float4*)p.e[0])[b4i];
    float4 vk = ((const float4*)p.e[1])[b4i];
    float4 vv = ((const float4*)p.e[2])[b4i];
    float a0 = alpha[el][0], a1 = alpha[el][1], a2 = alpha[el][2];
    float4 o;
    o.x = a0*va.x + a1*vk.x + a2*vv.x;
    o.y = a0*va.y + a1*vk.y + a2*vv.y;
    o.z = a0*va.z + a1*vk.z + a2*vv.z;
    o.w = a0*va.w + a1*vk.w + a2*vv.w;
    ((float4*)ee)[i4] = o;
  }
  __syncthreads();
  int jp = tid & 63, eg = tid >> 6;
  int j = jp * 2;
  float am[4][2], as[4][2];
#pragma unroll
  for (int r = 0; r < 4; ++r) { am[r][0]=am[r][1]=as[r][0]=as[r][1]=0.f; }
  for (int hh = 0; hh < D1; hh += 4) {
    float2 wm[4], ws[4];
#pragma unroll
    for (int q = 0; q < 4; ++q) {
      wm[q] = *(const float2*)&p.Wem[(size_t)(hh + q) * D2 + j];
      ws[q] = *(const float2*)&p.Wes[(size_t)(hh + q) * D2 + j];
    }
#pragma unroll
    for (int r = 0; r < 4; ++r) {
      const float4 ev = *(const float4*)&ee[(eg * 4 + r) * D1 + hh];
      am[r][0] += ev.x*wm[0].x + ev.y*wm[1].x + ev.z*wm[2].x + ev.w*wm[3].x;
      am[r][1] += ev.x*wm[0].y + ev.y*wm[1].y + ev.z*wm[2].y + ev.w*wm[3].y;
      as[r][0] += ev.x*ws[0].x + ev.y*ws[1].x + ev.z*ws[2].x + ev.w*ws[3].x;
      as[r][1] += ev.x*ws[0].y + ev.y*ws[1].y + ev.z*ws[2].y + ev.w*ws[3].y;
    }
  }
  float bm0 = p.bem[j], bm1 = p.bem[j+1], bs0 = p.bes[j], bs1 = p.bes[j+1];
#pragma unroll
  for (int r = 0; r < 4; ++r) {
    int e = e0 + eg * 4 + r;
    float zm0 = am[r][0] + bm0, zm1 = am[r][1] + bm1;
    float zs0 = as[r][0] + bs0, zs1 = as[r][1] + bs1;
    float e0v = p.eps_e[(size_t)e * D2 + j], e1v = p.eps_e[(size_t)e * D2 + j + 1];
    float z0 = zm0 + e0v * expf(zs0), z1 = zm1 + e1v * expf(zs1);
    size_t oi = (size_t)e * D2 + j;
    p.zembf[oi]   = __float2bfloat16(zm0); p.zembf[oi+1] = __float2bfloat16(zm1);
    p.zebf[oi]    = __float2bfloat16(z0);  p.zebf[oi+1]  = __float2bfloat16(z1);
  }
}

// out[M,4096] = A[M,128] @ B[4096,128]^T, bf16 MFMA 16x16x32.
// Block: 64x128 tile, 4 waves x (16 rows x 128 cols). C staged in LDS, written
// back as row-contiguous f32x4 nontemporal stores (512B per half-wave instr).
#define DT_N 128
__global__ __launch_bounds__(256) void decode_kernel(Params p) {
  __shared__ __align__(16) float cs[64][DT_N + 4];   // pad 132 -> 2-way banks on acc store
  int which = blockIdx.z;
  const __hip_bfloat16* A = which ? p.Zmbf  : p.Zbf;
  const __hip_bfloat16* B = which ? p.zembf : p.zebf;
  float* C = p.out + (size_t)which * MTOT * NE;
  int n0 = blockIdx.x * DT_N;
  int m0 = blockIdx.y * 64;
  int wid  = threadIdx.x >> 6;
  int lane = threadIdx.x & 63;
  int rloc = lane & 15;
  int kg   = lane >> 4;
  int mrow = m0 + wid * 16 + rloc;
  bf16x8 a[4];
#pragma unroll
  for (int kk = 0; kk < 4; ++kk)
    a[kk] = *(const bf16x8*)(A + (size_t)mrow * D2 + kk * 32 + kg * 8);
  f32x4 acc[DT_N / 16];
  f32x4 zero = {0.f, 0.f, 0.f, 0.f};
#pragma unroll
  for (int nf = 0; nf < DT_N / 16; ++nf) acc[nf] = zero;
#pragma unroll
  for (int nf = 0; nf < DT_N / 16; ++nf) {
    int ncol = n0 + nf * 16 + rloc;
#pragma unroll
    for (int kk = 0; kk < 4; ++kk) {
      bf16x8 bv = *(const bf16x8*)(B + (size_t)ncol * D2 + kk * 32 + kg * 8);
      acc[nf] = __builtin_amdgcn_mfma_f32_16x16x32_bf16(a[kk], bv, acc[nf], 0, 0, 0);
    }
  }
  // stage C tile: row_local = wid*16 + kg*4 + jj, col_local = nf*16 + rloc
#pragma unroll
  for (int nf = 0; nf < DT_N / 16; ++nf)
#pragma unroll
    for (int jj = 0; jj < 4; ++jj)
      cs[wid * 16 + kg * 4 + jj][nf * 16 + rloc] = acc[nf][jj];
  __syncthreads();
  // write back: 8 iters, half-wave per row -> 512B contiguous per instruction
  int r_l  = threadIdx.x >> 5;          // 0..7
  int c4   = (threadIdx.x & 31) * 4;    // 0..124
#pragma unroll
  for (int it = 0; it < 8; ++it) {
    int r = it * 8 + r_l;
    f32x4 v = *(const f32x4*)&cs[r][c4];
    __builtin_nontemporal_store(v, (f32x4*)&C[(size_t)(m0 + r) * NE + n0 + c4]);
  }
}

extern "C" void kernel_launch(void* const* d_in, const int* in_sizes, int n_in,
                              void* d_out, int out_size, void* d_ws, size_t ws_size,
                              hipStream_t stream) {
  (void)in_sizes; (void)n_in; (void)out_size; (void)ws_size;
  static const int Ns[3] = {8192, 4096, 1024};
  static const int NsegH[6] = {8192, 4096, 4096, 4096, 1024, 4096};

  Params p;
  for (int t = 0; t < 3; ++t) {
    const int o = t * 12;
    p.rows[t] = (const int*)d_in[o + 0];
    p.cols[t] = (const int*)d_in[o + 1];
    p.vals[t] = (const float*)d_in[o + 2];
    p.Wn[t]   = (const float*)d_in[o + 3];
    p.bn[t]   = (const float*)d_in[o + 4];
    p.Wzm[t]  = (const float*)d_in[o + 5];
    p.bzm[t]  = (const float*)d_in[o + 6];
    p.Wzs[t]  = (const float*)d_in[o + 7];
    p.bzs[t]  = (const float*)d_in[o + 8];
    p.We[t]   = (const float*)d_in[o + 9];
    p.be[t]   = (const float*)d_in[o + 10];
    p.eps[t]  = (const float*)d_in[o + 11];
  }
  p.Watt  = (const float*)d_in[36];
  p.batt  = (const float*)d_in[37];
  p.uatt  = (const float*)d_in[38];
  p.Wem   = (const float*)d_in[39];
  p.bem   = (const float*)d_in[40];
  p.Wes   = (const float*)d_in[41];
  p.bes   = (const float*)d_in[42];
  p.eps_e = (const float*)d_in[43];
  p.out = (float*)d_out;
  p.rowbase[0] = 0; p.rowbase[1] = 8192; p.rowbase[2] = 12288;

  char* ws = (char*)d_ws;
  size_t off = 0;
  auto alloc = [&](size_t bytes) -> char* {
    char* r = ws + off;
    off += (bytes + 255) & ~(size_t)255;
    return r;
  };
  // counter arrays first: one contiguous region, zeroed each call
  for (int s = 0; s < 6; ++s) p.cnt[s] = (int*)alloc((size_t)(NsegH[s] + 1) * 4);
  size_t cnt_bytes = off;
  for (int s = 0; s < 6; ++s) {
    p.ptr[s]   = (int*)alloc((size_t)(NsegH[s] + 1) * 4);
    p.cur[s]   = (int*)alloc((size_t)(NsegH[s] + 1) * 4);
    p.spair[s] = (int2*)alloc((size_t)NNZV * 8);
  }
  for (int t = 0; t < 3; ++t) p.h[t] = (float*)alloc((size_t)Ns[t] * D1 * 4);
  for (int t = 0; t < 3; ++t) p.e[t] = (float*)alloc((size_t)NE * D1 * 4);
  p.scores = (float*)alloc((size_t)NE * 3 * 4);
  p.Zbf    = (__hip_bfloat16*)alloc((size_t)MTOT * D2 * 2);
  p.Zmbf   = (__hip_bfloat16*)alloc((size_t)MTOT * D2 * 2);
  p.zebf   = (__hip_bfloat16*)alloc((size_t)NE * D2 * 2);
  p.zembf  = (__hip_bfloat16*)alloc((size_t)NE * D2 * 2);

  (void)hipMemsetAsync(d_ws, 0, cnt_bytes, stream);
  hist_kernel   <<<(6 * NNZV + 255) / 256, 256, 0, stream>>>(p);
  scan_kernel   <<<6, 1024, 0, stream>>>(p);
  scatter_kernel<<<(6 * NNZV + 255) / 256, 256, 0, stream>>>(p);
  spmm_kernel   <<<25600, 128, 0, stream>>>(p);
  zmzs_kernel   <<<416, 256, 0, stream>>>(p);
  scores_kernel <<<512, 256, 0, stream>>>(p);
  combine_kernel<<<256, 256, 0, stream>>>(p);
  decode_kernel <<<dim3(NE / DT_N, 208, 2), 256, 0, stream>>>(p);
}